// Round 21
// baseline (210.585 us; speedup 1.0000x reference)
//
#include <hip/hip_runtime.h>

// MultiHeadAttention with ALiBi: B=16, N=1024, C=768, H=12, D=64
// QKV GEMM with FUSED f32->bf16 staging (reg-stage + cvt_pk + ds_write,
// double-buffered LDS, swizzled) -> flash attn (r14 verified) -> proj GEMM
// (r20 verified gl16 path; w_proj converted by a tiny cvt kernel)

typedef unsigned short u16;
typedef unsigned int u32;
typedef __attribute__((ext_vector_type(8))) short short8;
typedef __attribute__((ext_vector_type(4))) float f32x4;

__device__ __forceinline__ u16 f2bf(float f) {
    u32 u = __float_as_uint(f);
    u32 r = u + 0x7FFFu + ((u >> 16) & 1u);  // RNE
    return (u16)(r >> 16);
}

__device__ __forceinline__ f32x4 mfma16(short8 a, short8 b, f32x4 c) {
    return __builtin_amdgcn_mfma_f32_16x16x32_bf16(a, b, c, 0, 0, 0);
}
__device__ __forceinline__ u32 cvtpk_bf16(float lo, float hi) {
    u32 r;
    asm("v_cvt_pk_bf16_f32 %0, %1, %2" : "=v"(r) : "v"(lo), "v"(hi));
    return r;
}

typedef __attribute__((address_space(1))) const unsigned int gu32_t;
typedef __attribute__((address_space(3))) unsigned int su32_t;
__device__ __forceinline__ void gl16(const u16* g, u16* s) {
    __builtin_amdgcn_global_load_lds((gu32_t*)g, (su32_t*)s, 16, 0, 0);
}

// ---------------- tiny cvt: w_proj only (147456 float4) -----------------------
__global__ void cvt_wp(const float* __restrict__ wp, u16* __restrict__ Wprojb) {
    int idx = blockIdx.x * blockDim.x + threadIdx.x;   // 576*256 = 147456 exact
    float4 v = *(const float4*)(wp + (size_t)idx * 4);
    ushort4 o;
    o.x = f2bf(v.x); o.y = f2bf(v.y); o.z = f2bf(v.z); o.w = f2bf(v.w);
    *(ushort4*)(Wprojb + (size_t)idx * 4) = o;
}

// ---------------- QKV GEMM, f32 inputs, fused conversion ----------------------
// 128x128 tile, BK=32, 8 waves (2m x 4n of 64x32). Reg-staged f32 A/B panels
// (4 float4/thread/tile), v_cvt_pk_bf16_f32, ds_write_b128 into DOUBLE-buffered
// LDS (32 KB). Single staged batch in flight; loads issued one full iteration
// before their vmcnt(0) drain. r20 slot-swizzle kept (write slot linear,
// source slot ^f(row), read col ^f(row)).
__global__ __launch_bounds__(512) void gemm_qkv(
    const float* __restrict__ A, const float* __restrict__ Bw,
    const float* __restrict__ bias, u16* __restrict__ outb, int nTilesN)
{
    constexpr int K = 768;
    constexpr int nkt = K / 32;      // 24
    __shared__ __align__(16) u16 lA[2][128 * 32];
    __shared__ __align__(16) u16 lB[2][128 * 32];

    int tid = threadIdx.x;
    int bid = blockIdx.x;
    int nwg = gridDim.x;
    int cpx = nwg >> 3;
    int swz = (bid & 7) * cpx + (bid >> 3);  // XCD swizzle (nwg % 8 == 0)
    int bm = swz / nTilesN;
    int bn = swz - bm * nTilesN;
    int m0 = bm * 128, n0 = bn * 128;

    int sr = tid >> 2;               // staging row 0..127
    int sc = (((tid & 3) ^ ((sr >> 1) & 3)) << 3);   // swizzled source slot (f32)
    const float* pA = A + (size_t)(m0 + sr) * K + sc;
    const float* pB = Bw + (size_t)(n0 + sr) * K + sc;
    int lo = tid * 8;                // linear LDS bf16 elem offset

    // prologue: tile 0 regs -> cvt -> buf0; then issue tile 1 loads
    float4 a0 = *(const float4*)(pA);
    float4 a1 = *(const float4*)(pA + 4);
    float4 b0 = *(const float4*)(pB);
    float4 b1 = *(const float4*)(pB + 4);
    asm volatile("s_waitcnt vmcnt(0)" ::: "memory");
    {
        uint4 wa, wb;
        wa.x = cvtpk_bf16(a0.x, a0.y); wa.y = cvtpk_bf16(a0.z, a0.w);
        wa.z = cvtpk_bf16(a1.x, a1.y); wa.w = cvtpk_bf16(a1.z, a1.w);
        wb.x = cvtpk_bf16(b0.x, b0.y); wb.y = cvtpk_bf16(b0.z, b0.w);
        wb.z = cvtpk_bf16(b1.x, b1.y); wb.w = cvtpk_bf16(b1.z, b1.w);
        *(uint4*)&lA[0][lo] = wa;
        *(uint4*)&lB[0][lo] = wb;
    }
    a0 = *(const float4*)(pA + 32);
    a1 = *(const float4*)(pA + 36);
    b0 = *(const float4*)(pB + 32);
    b1 = *(const float4*)(pB + 36);

    int w = tid >> 6, lane = tid & 63;
    int wm = w >> 2, wn = w & 3;     // wave tile: rows wm*64+, cols wn*32+
    int fq = lane >> 4, fr = lane & 15;
    int fsw = (fr >> 1) & 3;         // read-side swizzle factor (lane-const)
    int colA = (fq ^ fsw) << 3;
    f32x4 acc[4][2] = {};

    for (int kt = 0; kt < nkt; ++kt) {
        int p = kt & 1;
        // publish buf[p] (ds_writes from prev iter) to all waves
        asm volatile("s_waitcnt lgkmcnt(0)" ::: "memory");
        __builtin_amdgcn_sched_barrier(0);
        __builtin_amdgcn_s_barrier();
        __builtin_amdgcn_sched_barrier(0);

        short8 af[4], bfr[2];
#pragma unroll
        for (int i = 0; i < 4; ++i)
            af[i] = *(const short8*)&lA[p][(wm * 64 + i * 16 + fr) * 32 + colA];
#pragma unroll
        for (int j = 0; j < 2; ++j)
            bfr[j] = *(const short8*)&lB[p][(wn * 32 + j * 16 + fr) * 32 + colA];

        // drain tile kt+1 regs (issued one iter ago), convert, write buf[p^1]
        if (kt + 1 < nkt) {
            asm volatile("s_waitcnt vmcnt(0)" ::: "memory");
            uint4 wa, wb;
            wa.x = cvtpk_bf16(a0.x, a0.y); wa.y = cvtpk_bf16(a0.z, a0.w);
            wa.z = cvtpk_bf16(a1.x, a1.y); wa.w = cvtpk_bf16(a1.z, a1.w);
            wb.x = cvtpk_bf16(b0.x, b0.y); wb.y = cvtpk_bf16(b0.z, b0.w);
            wb.z = cvtpk_bf16(b1.x, b1.y); wb.w = cvtpk_bf16(b1.z, b1.w);
            *(uint4*)&lA[p ^ 1][lo] = wa;
            *(uint4*)&lB[p ^ 1][lo] = wb;
        }
        // issue tile kt+2 loads (anti-dependency on a0..b1 orders after cvt)
        if (kt + 2 < nkt) {
            a0 = *(const float4*)(pA + (kt + 2) * 32);
            a1 = *(const float4*)(pA + (kt + 2) * 32 + 4);
            b0 = *(const float4*)(pB + (kt + 2) * 32);
            b1 = *(const float4*)(pB + (kt + 2) * 32 + 4);
        }

        __builtin_amdgcn_s_setprio(1);
#pragma unroll
        for (int i = 0; i < 4; ++i)
#pragma unroll
            for (int j = 0; j < 2; ++j)
                acc[i][j] = mfma16(af[i], bfr[j], acc[i][j]);
        __builtin_amdgcn_s_setprio(0);
    }

    // epilogue: scatter to QKV [s][16][12][1024][64] + bias
    {
        int b = m0 >> 10;
        int i0 = (m0 & 1023) + wm * 64;
#pragma unroll
        for (int j = 0; j < 2; ++j) {
            int colb = n0 + wn * 32 + j * 16;      // multiple of 16
            int s = colb / 768;
            int rem = colb % 768;                  // rem+15 < 768
            int hh = rem >> 6;
            int d0 = rem & 63;
            float bval = bias[colb + fr];
            u16* obase = outb + (((size_t)s * 16 + b) * 12 + hh) * 65536;
#pragma unroll
            for (int i = 0; i < 4; ++i) {
                int r0 = i0 + i * 16 + fq * 4;
#pragma unroll
                for (int r = 0; r < 4; ++r)
                    obase[(size_t)(r0 + r) * 64 + d0 + fr] = f2bf(acc[i][j][r] + bval);
            }
        }
    }
}

// ---------------- NT GEMM (r20 verified, bf16 gl16 path; proj only) -----------
template <int EPI>
__global__ __launch_bounds__(512) void gemm_nt(
    const u16* __restrict__ A, const u16* __restrict__ Bw,
    const float* __restrict__ bias, u16* __restrict__ outb, float* __restrict__ outf,
    int nTilesN)
{
    constexpr int K = 768;
    constexpr int nkt = K / 32;      // 24
    __shared__ __align__(16) u16 lA[3][128 * 32];
    __shared__ __align__(16) u16 lB[3][128 * 32];

    int tid = threadIdx.x;
    int bid = blockIdx.x;
    int nwg = gridDim.x;
    int cpx = nwg >> 3;
    int swz = (bid & 7) * cpx + (bid >> 3);  // XCD swizzle (nwg % 8 == 0)
    int bm = swz / nTilesN;
    int bn = swz - bm * nTilesN;
    int m0 = bm * 128, n0 = bn * 128;

    int sr = tid >> 2;
    int sc = (((tid & 3) ^ ((sr >> 1) & 3)) << 3);
    const u16* pA = A + (size_t)(m0 + sr) * K + sc;
    const u16* pB = Bw + (size_t)(n0 + sr) * K + sc;
    int lo = tid * 8;

    gl16(pA,      &lA[0][lo]);
    gl16(pB,      &lB[0][lo]);
    gl16(pA + 32, &lA[1][lo]);
    gl16(pB + 32, &lB[1][lo]);

    int w = tid >> 6, lane = tid & 63;
    int wm = w >> 2, wn = w & 3;
    int fq = lane >> 4, fr = lane & 15;
    int fsw = (fr >> 1) & 3;
    int colA = (fq ^ fsw) << 3;
    f32x4 acc[4][2] = {};

    for (int kt = 0; kt < nkt; ++kt) {
        int cur = kt % 3;
        if (kt < nkt - 1) { asm volatile("s_waitcnt vmcnt(2)" ::: "memory"); }
        else              { asm volatile("s_waitcnt vmcnt(0)" ::: "memory"); }
        __builtin_amdgcn_sched_barrier(0);
        __builtin_amdgcn_s_barrier();
        __builtin_amdgcn_sched_barrier(0);
        if (kt + 2 < nkt) {
            int nx = (kt + 2) % 3;
            gl16(pA + (kt + 2) * 32, &lA[nx][lo]);
            gl16(pB + (kt + 2) * 32, &lB[nx][lo]);
        }
        short8 af[4], bfr[2];
#pragma unroll
        for (int i = 0; i < 4; ++i)
            af[i] = *(const short8*)&lA[cur][(wm * 64 + i * 16 + fr) * 32 + colA];
#pragma unroll
        for (int j = 0; j < 2; ++j)
            bfr[j] = *(const short8*)&lB[cur][(wn * 32 + j * 16 + fr) * 32 + colA];
        __builtin_amdgcn_s_setprio(1);
#pragma unroll
        for (int i = 0; i < 4; ++i)
#pragma unroll
            for (int j = 0; j < 2; ++j)
                acc[i][j] = mfma16(af[i], bfr[j], acc[i][j]);
        __builtin_amdgcn_s_setprio(0);
    }

    if (EPI == 0) {
        int b = m0 >> 10;
        int i0 = (m0 & 1023) + wm * 64;
#pragma unroll
        for (int j = 0; j < 2; ++j) {
            int colb = n0 + wn * 32 + j * 16;
            int s = colb / 768;
            int rem = colb % 768;
            int hh = rem >> 6;
            int d0 = rem & 63;
            float bval = bias[colb + fr];
            u16* obase = outb + (((size_t)s * 16 + b) * 12 + hh) * 65536;
#pragma unroll
            for (int i = 0; i < 4; ++i) {
                int r0 = i0 + i * 16 + fq * 4;
#pragma unroll
                for (int r = 0; r < 4; ++r)
                    obase[(size_t)(r0 + r) * 64 + d0 + fr] = f2bf(acc[i][j][r] + bval);
            }
        }
    } else {
#pragma unroll
        for (int j = 0; j < 2; ++j) {
            int col = n0 + wn * 32 + j * 16 + fr;
            float bval = bias[col];
#pragma unroll
            for (int i = 0; i < 4; ++i) {
                int row0 = m0 + wm * 64 + i * 16 + fq * 4;
#pragma unroll
                for (int r = 0; r < 4; ++r)
                    outf[(size_t)(row0 + r) * 768 + col] = acc[i][j][r] + bval;
            }
        }
    }
}

// ---------------- Flash attention with ALiBi (QBLK=128, 8 waves; r14) ---------
__global__ __launch_bounds__(512) void attn_alibi(
    const u16* __restrict__ QKV, u16* __restrict__ att)
{
    int g = blockIdx.x;              // 1536 = 8 XCDs * 24 bh * 8 qt
    int xcd = g & 7;
    int idx = g >> 3;
    int qt = idx & 7;
    int bh = xcd * 24 + (idx >> 3);  // bijective remap
    int h = bh % 12;
    int b = bh / 12;
    int q0 = qt * 128;
    const u16* Qg = QKV + (size_t)bh * 65536;
    const u16* Kg = QKV + (size_t)(192 + bh) * 65536;
    const u16* Vg = QKV + (size_t)(384 + bh) * 65536;

    __shared__ __align__(16) u16 Ks[64][72];
    __shared__ __align__(16) u16 Vt[64][72];   // Vt[d][kv ^ ((d>>3)<<3)]
    __shared__ __align__(16) u16 Ps[128][72];

    int tid = threadIdx.x, w = tid >> 6, lane = tid & 63;
    int fq = lane >> 4, fr = lane & 15;

    short8 aq0 = *(const short8*)(Qg + (size_t)(q0 + w * 16 + fr) * 64 + fq * 8);
    short8 aq1 = *(const short8*)(Qg + (size_t)(q0 + w * 16 + fr) * 64 + 32 + fq * 8);

    const float C1 = 0.125f * 1.44269504f;       // scale * log2(e)
    float c2 = __builtin_amdgcn_exp2f(-(2.0f / 3.0f) * (float)(h + 1)) * 1.44269504f;
    int distThr = (int)(40.0f / c2);
    int lo_kv = q0 - 63 - distThr;
    int hi_kv = q0 + 127 + distThr;
    int t_lo = (lo_kv <= 0) ? 0 : (lo_kv >> 6);
    int t_hi = (hi_kv >= 1023) ? 15 : (hi_kv >> 6);

    bool isK = tid < 256;
    int t2 = tid & 255;
    int sr0 = t2 >> 3;               // 0..31
    int sc = (t2 & 7) * 8;
    int vswz = (t2 & 7) << 3;
    int vk0 = sr0 * 2;
    int vcol = vk0 ^ vswz;
    const u16* g0 = isK ? (Kg + (size_t)sr0 * 64 + sc)
                        : (Vg + (size_t)vk0 * 64 + sc);
    const u16* g1 = isK ? (Kg + (size_t)(sr0 + 32) * 64 + sc)
                        : (Vg + (size_t)(vk0 + 1) * 64 + sc);

    uint4 r0 = *(const uint4*)(g0 + (size_t)t_lo * 4096);
    uint4 r1 = *(const uint4*)(g1 + (size_t)t_lo * 4096);

    float di = (float)(q0 + w * 16 + fr - fq * 4);
    float lsum = 0.f;
    f32x4 acc[4] = {};

    for (int it = t_lo; it <= t_hi; ++it) {
        __syncthreads();
        if (isK) {
            *(uint4*)&Ks[sr0][sc] = r0;
            *(uint4*)&Ks[sr0 + 32][sc] = r1;
        } else {
            const u16* v0 = (const u16*)&r0;
            const u16* v1 = (const u16*)&r1;
#pragma unroll
            for (int jj = 0; jj < 8; ++jj)
                *(u32*)&Vt[sc + jj][vcol] = (u32)v0[jj] | ((u32)v1[jj] << 16);
        }
        __syncthreads();

        if (it < t_hi) {
            r0 = *(const uint4*)(g0 + (size_t)(it + 1) * 4096);
            r1 = *(const uint4*)(g1 + (size_t)(it + 1) * 4096);
        }

        f32x4 sfr[4];
        __builtin_amdgcn_s_setprio(1);
#pragma unroll
        for (int ct = 0; ct < 4; ++ct) {
            short8 bk0 = *(const short8*)&Ks[ct * 16 + fr][fq * 8];
            short8 bk1 = *(const short8*)&Ks[ct * 16 + fr][32 + fq * 8];
            f32x4 s0 = {0.f, 0.f, 0.f, 0.f};
            s0 = mfma16(bk0, aq0, s0);      // swapped: A=K, B=Q
            s0 = mfma16(bk1, aq1, s0);
            sfr[ct] = s0;
        }
        __builtin_amdgcn_s_setprio(0);

        float dkv = di - (float)(it * 64);
#pragma unroll
        for (int ct = 0; ct < 4; ++ct) {
            float t0 = dkv - (float)(ct * 16);
            float e0 = __builtin_amdgcn_exp2f(fmaf(sfr[ct][0], C1, -c2 * fabsf(t0)));
            float e1 = __builtin_amdgcn_exp2f(fmaf(sfr[ct][1], C1, -c2 * fabsf(t0 - 1.0f)));
            float e2 = __builtin_amdgcn_exp2f(fmaf(sfr[ct][2], C1, -c2 * fabsf(t0 - 2.0f)));
            float e3 = __builtin_amdgcn_exp2f(fmaf(sfr[ct][3], C1, -c2 * fabsf(t0 - 3.0f)));
            lsum += (e0 + e1) + (e2 + e3);
            uint2 pk;
            pk.x = cvtpk_bf16(e0, e1);
            pk.y = cvtpk_bf16(e2, e3);
            *(uint2*)&Ps[w * 16 + fr][ct * 16 + fq * 4] = pk;
        }

        short8 pa0 = *(const short8*)&Ps[w * 16 + fr][fq * 8];
        short8 pa1 = *(const short8*)&Ps[w * 16 + fr][32 + fq * 8];
        __builtin_amdgcn_s_setprio(1);
#pragma unroll
        for (int dt = 0; dt < 4; ++dt) {
            int row = dt * 16 + fr;
            int swzr = (row >> 3) << 3;
            short8 bv0 = *(const short8*)&Vt[row][(fq * 8) ^ swzr];
            short8 bv1 = *(const short8*)&Vt[row][(32 + fq * 8) ^ swzr];
            acc[dt] = mfma16(pa0, bv0, acc[dt]);
            acc[dt] = mfma16(pa1, bv1, acc[dt]);
        }
        __builtin_amdgcn_s_setprio(0);
    }

    float l = lsum;
    l += __shfl_xor(l, 16);
    l += __shfl_xor(l, 32);
    float rlo = 1.0f / l;
    float rl[4];
#pragma unroll
    for (int r = 0; r < 4; ++r)
        rl[r] = __shfl(rlo, fq * 4 + r);

#pragma unroll
    for (int dt = 0; dt < 4; ++dt)
#pragma unroll
        for (int r = 0; r < 4; ++r) {
            int ig = q0 + w * 16 + fq * 4 + r;
            att[((size_t)(b * 1024 + ig) * 12 + h) * 64 + dt * 16 + fr] =
                (u16)cvtpk_bf16(acc[dt][r] * rl[r], 0.f);
        }
}

extern "C" void kernel_launch(void* const* d_in, const int* in_sizes, int n_in,
                              void* d_out, int out_size, void* d_ws, size_t ws_size,
                              hipStream_t stream) {
    const float* x      = (const float*)d_in[0];  // [16,1024,768]
    const float* w_qkv  = (const float*)d_in[1];  // [2304,768]
    const float* b_qkv  = (const float*)d_in[2];  // [2304]
    const float* w_proj = (const float*)d_in[3];  // [768,768]
    const float* b_proj = (const float*)d_in[4];  // [768]
    float* out = (float*)d_out;                   // [16,1024,768]

    char* ws = (char*)d_ws;
    u16* Attb   = (u16*)ws;                        // attn output [16384][768]
    u16* Wprojb = (u16*)(ws + 28704768);
    u16* QKVb   = (u16*)(ws + 29884416);           // [3][16][12][1024][64]

    cvt_wp<<<576, 256, 0, stream>>>(w_proj, Wprojb);

    gemm_qkv<<<128 * 18, 512, 0, stream>>>(x, w_qkv, b_qkv, QKVb, 18);
    attn_alibi<<<1536, 512, 0, stream>>>(QKVb, Attb);
    gemm_nt<1><<<128 * 6, 512, 0, stream>>>(Attb, Wprojb, b_proj, nullptr, out, 6);
}

// Round 22
// 189.813 us; speedup vs baseline: 1.1094x; 1.1094x over previous
//
#include <hip/hip_runtime.h>

// MultiHeadAttention with ALiBi: B=16, N=1024, C=768, H=12, D=64
// cvt(fused) -> QKV GEMM (128x128, 8 waves, global_load_lds + vmcnt(2) triple
//               buffer, slot-swizzled LDS: bank-conflict-free) -> flash attn
//               (QBLK=128, 8 waves, wave-split staging) -> proj GEMM
// [round-20 verified configuration — session best, all axes bracketed]

typedef unsigned short u16;
typedef unsigned int u32;
typedef __attribute__((ext_vector_type(8))) short short8;
typedef __attribute__((ext_vector_type(4))) float f32x4;

__device__ __forceinline__ u16 f2bf(float f) {
    u32 u = __float_as_uint(f);
    u32 r = u + 0x7FFFu + ((u >> 16) & 1u);  // RNE
    return (u16)(r >> 16);
}

__device__ __forceinline__ f32x4 mfma16(short8 a, short8 b, f32x4 c) {
    return __builtin_amdgcn_mfma_f32_16x16x32_bf16(a, b, c, 0, 0, 0);
}
__device__ __forceinline__ u32 cvtpk_bf16(float lo, float hi) {
    u32 r;
    asm("v_cvt_pk_bf16_f32 %0, %1, %2" : "=v"(r) : "v"(lo), "v"(hi));
    return r;
}

typedef __attribute__((address_space(1))) const unsigned int gu32_t;
typedef __attribute__((address_space(3))) unsigned int su32_t;
__device__ __forceinline__ void gl16(const u16* g, u16* s) {
    __builtin_amdgcn_global_load_lds((gu32_t*)g, (su32_t*)s, 16, 0, 0);
}

// ---------------- fused f32 -> bf16 convert (3 tensors, one launch) ----------
__global__ void cvt_all(const float* __restrict__ x, const float* __restrict__ wq,
                        const float* __restrict__ wp, u16* __restrict__ Xb,
                        u16* __restrict__ Wqkvb, u16* __restrict__ Wprojb) {
    int i = blockIdx.x * blockDim.x + threadIdx.x;
    int stride = gridDim.x * blockDim.x;
    for (int idx = i; idx < 3735552; idx += stride) {
        const float* src;
        u16* dst;
        int k;
        if (idx < 3145728) { src = x; dst = Xb; k = idx; }
        else if (idx < 3588096) { src = wq; dst = Wqkvb; k = idx - 3145728; }
        else { src = wp; dst = Wprojb; k = idx - 3588096; }
        float4 v = *(const float4*)(src + (size_t)k * 4);
        ushort4 o;
        o.x = f2bf(v.x); o.y = f2bf(v.y); o.z = f2bf(v.z); o.w = f2bf(v.w);
        *(ushort4*)(dst + (size_t)k * 4) = o;
    }
}

// ---------------- NT GEMM (r20 verified: skeleton + T2 slot swizzle) ----------
// 128x128 tile, BK=32, 8 waves (2m x 4n of 64x32). Triple-buffered
// global_load_lds, counted vmcnt(2) + raw barrier. Rule-#21 swizzle pair:
// LDS[row][slot] holds global[row][slot ^ ((row>>1)&3)] (linear gl16 dest +
// pre-swizzled SOURCE), fragment reads XOR the same factor -> 0 bank conflicts.
template <int EPI>
__global__ __launch_bounds__(512) void gemm_nt(
    const u16* __restrict__ A, const u16* __restrict__ Bw,
    const float* __restrict__ bias, u16* __restrict__ outb, float* __restrict__ outf,
    int nTilesN)
{
    constexpr int K = 768;
    constexpr int nkt = K / 32;      // 24
    __shared__ __align__(16) u16 lA[3][128 * 32];
    __shared__ __align__(16) u16 lB[3][128 * 32];

    int tid = threadIdx.x;
    int bid = blockIdx.x;
    int nwg = gridDim.x;
    int cpx = nwg >> 3;
    int swz = (bid & 7) * cpx + (bid >> 3);  // XCD swizzle (nwg % 8 == 0)
    int bm = swz / nTilesN;
    int bn = swz - bm * nTilesN;
    int m0 = bm * 128, n0 = bn * 128;

    int sr = tid >> 2;               // staging row 0..127
    int sc = (((tid & 3) ^ ((sr >> 1) & 3)) << 3);   // pre-swizzled source slot
    const u16* pA = A + (size_t)(m0 + sr) * K + sc;
    const u16* pB = Bw + (size_t)(n0 + sr) * K + sc;
    int lo = tid * 8;                // LINEAR LDS dest

    gl16(pA,      &lA[0][lo]);
    gl16(pB,      &lB[0][lo]);
    gl16(pA + 32, &lA[1][lo]);
    gl16(pB + 32, &lB[1][lo]);

    int w = tid >> 6, lane = tid & 63;
    int wm = w >> 2, wn = w & 3;     // wave tile: rows wm*64+, cols wn*32+
    int fq = lane >> 4, fr = lane & 15;
    int fsw = (fr >> 1) & 3;         // read-side swizzle factor (lane-const)
    int colA = (fq ^ fsw) << 3;
    f32x4 acc[4][2] = {};

    for (int kt = 0; kt < nkt; ++kt) {
        int cur = kt % 3;
        if (kt < nkt - 1) { asm volatile("s_waitcnt vmcnt(2)" ::: "memory"); }
        else              { asm volatile("s_waitcnt vmcnt(0)" ::: "memory"); }
        __builtin_amdgcn_sched_barrier(0);
        __builtin_amdgcn_s_barrier();
        __builtin_amdgcn_sched_barrier(0);
        if (kt + 2 < nkt) {
            int nx = (kt + 2) % 3;
            gl16(pA + (kt + 2) * 32, &lA[nx][lo]);
            gl16(pB + (kt + 2) * 32, &lB[nx][lo]);
        }
        short8 af[4], bfr[2];
#pragma unroll
        for (int i = 0; i < 4; ++i)
            af[i] = *(const short8*)&lA[cur][(wm * 64 + i * 16 + fr) * 32 + colA];
#pragma unroll
        for (int j = 0; j < 2; ++j)
            bfr[j] = *(const short8*)&lB[cur][(wn * 32 + j * 16 + fr) * 32 + colA];
        __builtin_amdgcn_s_setprio(1);
#pragma unroll
        for (int i = 0; i < 4; ++i)
#pragma unroll
            for (int j = 0; j < 2; ++j)
                acc[i][j] = mfma16(af[i], bfr[j], acc[i][j]);
        __builtin_amdgcn_s_setprio(0);
    }

    if (EPI == 0) {
        int b = m0 >> 10;
        int i0 = (m0 & 1023) + wm * 64;
#pragma unroll
        for (int j = 0; j < 2; ++j) {
            int colb = n0 + wn * 32 + j * 16;      // multiple of 16
            int s = colb / 768;
            int rem = colb % 768;                  // rem+15 < 768
            int hh = rem >> 6;
            int d0 = rem & 63;
            float bval = bias[colb + fr];
            u16* obase = outb + (((size_t)s * 16 + b) * 12 + hh) * 65536;
#pragma unroll
            for (int i = 0; i < 4; ++i) {
                int r0 = i0 + i * 16 + fq * 4;
#pragma unroll
                for (int r = 0; r < 4; ++r)
                    obase[(size_t)(r0 + r) * 64 + d0 + fr] = f2bf(acc[i][j][r] + bval);
            }
        }
    } else {
#pragma unroll
        for (int j = 0; j < 2; ++j) {
            int col = n0 + wn * 32 + j * 16 + fr;
            float bval = bias[col];
#pragma unroll
            for (int i = 0; i < 4; ++i) {
                int row0 = m0 + wm * 64 + i * 16 + fq * 4;
#pragma unroll
                for (int r = 0; r < 4; ++r)
                    outf[(size_t)(row0 + r) * 768 + col] = acc[i][j][r] + bval;
            }
        }
    }
}

// ---------------- Flash attention with ALiBi (QBLK=128, 8 waves; r14) ---------
// Block = 8 waves, one (b,h,qt): 128 q rows. Waves 0-3 stage K, waves 4-7 stage
// V pairs (b32 packed transpose). K/V prefetched to regs one tile ahead
// (staging keeps global latency OFF the MFMA-dependent path — r16 lesson).
__global__ __launch_bounds__(512) void attn_alibi(
    const u16* __restrict__ QKV, u16* __restrict__ att)
{
    int g = blockIdx.x;              // 1536 = 8 XCDs * 24 bh * 8 qt
    int xcd = g & 7;
    int idx = g >> 3;
    int qt = idx & 7;
    int bh = xcd * 24 + (idx >> 3);  // bijective remap
    int h = bh % 12;
    int b = bh / 12;
    int q0 = qt * 128;
    const u16* Qg = QKV + (size_t)bh * 65536;
    const u16* Kg = QKV + (size_t)(192 + bh) * 65536;
    const u16* Vg = QKV + (size_t)(384 + bh) * 65536;

    __shared__ __align__(16) u16 Ks[64][72];
    __shared__ __align__(16) u16 Vt[64][72];   // Vt[d][kv ^ ((d>>3)<<3)]
    __shared__ __align__(16) u16 Ps[128][72];

    int tid = threadIdx.x, w = tid >> 6, lane = tid & 63;
    int fq = lane >> 4, fr = lane & 15;

    short8 aq0 = *(const short8*)(Qg + (size_t)(q0 + w * 16 + fr) * 64 + fq * 8);
    short8 aq1 = *(const short8*)(Qg + (size_t)(q0 + w * 16 + fr) * 64 + 32 + fq * 8);

    const float C1 = 0.125f * 1.44269504f;       // scale * log2(e)
    float c2 = __builtin_amdgcn_exp2f(-(2.0f / 3.0f) * (float)(h + 1)) * 1.44269504f;
    int distThr = (int)(40.0f / c2);
    int lo_kv = q0 - 63 - distThr;
    int hi_kv = q0 + 127 + distThr;
    int t_lo = (lo_kv <= 0) ? 0 : (lo_kv >> 6);
    int t_hi = (hi_kv >= 1023) ? 15 : (hi_kv >> 6);

    bool isK = tid < 256;
    int t2 = tid & 255;
    int sr0 = t2 >> 3;               // 0..31
    int sc = (t2 & 7) * 8;
    int vswz = (t2 & 7) << 3;        // XOR of kv bits 3..5 (pair-preserving)
    int vk0 = sr0 * 2;               // V rows vk0, vk0+1
    int vcol = vk0 ^ vswz;           // even; b32 spans kv pair
    const u16* g0 = isK ? (Kg + (size_t)sr0 * 64 + sc)
                        : (Vg + (size_t)vk0 * 64 + sc);
    const u16* g1 = isK ? (Kg + (size_t)(sr0 + 32) * 64 + sc)
                        : (Vg + (size_t)(vk0 + 1) * 64 + sc);

    uint4 r0 = *(const uint4*)(g0 + (size_t)t_lo * 4096);
    uint4 r1 = *(const uint4*)(g1 + (size_t)t_lo * 4096);

    float di = (float)(q0 + w * 16 + fr - fq * 4);
    float lsum = 0.f;
    f32x4 acc[4] = {};

    for (int it = t_lo; it <= t_hi; ++it) {
        __syncthreads();             // prev tile's LDS reads done
        if (isK) {
            *(uint4*)&Ks[sr0][sc] = r0;
            *(uint4*)&Ks[sr0 + 32][sc] = r1;
        } else {
            const u16* v0 = (const u16*)&r0;
            const u16* v1 = (const u16*)&r1;
#pragma unroll
            for (int jj = 0; jj < 8; ++jj)
                *(u32*)&Vt[sc + jj][vcol] = (u32)v0[jj] | ((u32)v1[jj] << 16);
        }
        __syncthreads();             // staged tile visible

        if (it < t_hi) {             // issue next tile's loads (hide under compute)
            r0 = *(const uint4*)(g0 + (size_t)(it + 1) * 4096);
            r1 = *(const uint4*)(g1 + (size_t)(it + 1) * 4096);
        }

        // S^T tile: lane holds S^T[kv=ct*16+fq*4+r][q=w*16+fr]
        f32x4 sfr[4];
        __builtin_amdgcn_s_setprio(1);
#pragma unroll
        for (int ct = 0; ct < 4; ++ct) {
            short8 bk0 = *(const short8*)&Ks[ct * 16 + fr][fq * 8];
            short8 bk1 = *(const short8*)&Ks[ct * 16 + fr][32 + fq * 8];
            f32x4 s0 = {0.f, 0.f, 0.f, 0.f};
            s0 = mfma16(bk0, aq0, s0);      // swapped: A=K, B=Q
            s0 = mfma16(bk1, aq1, s0);
            sfr[ct] = s0;
        }
        __builtin_amdgcn_s_setprio(0);

        // streaming softmax: p = exp2(s*C1 - c2*|i-j|), scalar l, uint2 P writes
        float dkv = di - (float)(it * 64);
#pragma unroll
        for (int ct = 0; ct < 4; ++ct) {
            float t0 = dkv - (float)(ct * 16);
            float e0 = __builtin_amdgcn_exp2f(fmaf(sfr[ct][0], C1, -c2 * fabsf(t0)));
            float e1 = __builtin_amdgcn_exp2f(fmaf(sfr[ct][1], C1, -c2 * fabsf(t0 - 1.0f)));
            float e2 = __builtin_amdgcn_exp2f(fmaf(sfr[ct][2], C1, -c2 * fabsf(t0 - 2.0f)));
            float e3 = __builtin_amdgcn_exp2f(fmaf(sfr[ct][3], C1, -c2 * fabsf(t0 - 3.0f)));
            lsum += (e0 + e1) + (e2 + e3);
            uint2 pk;
            pk.x = cvtpk_bf16(e0, e1);
            pk.y = cvtpk_bf16(e2, e3);
            *(uint2*)&Ps[w * 16 + fr][ct * 16 + fq * 4] = pk;
        }

        // PV (Ps rows wave-private; in-wave DS ordering suffices — no barrier)
        short8 pa0 = *(const short8*)&Ps[w * 16 + fr][fq * 8];
        short8 pa1 = *(const short8*)&Ps[w * 16 + fr][32 + fq * 8];
        __builtin_amdgcn_s_setprio(1);
#pragma unroll
        for (int dt = 0; dt < 4; ++dt) {
            int row = dt * 16 + fr;
            int swzr = (row >> 3) << 3;
            short8 bv0 = *(const short8*)&Vt[row][(fq * 8) ^ swzr];
            short8 bv1 = *(const short8*)&Vt[row][(32 + fq * 8) ^ swzr];
            acc[dt] = mfma16(pa0, bv0, acc[dt]);
            acc[dt] = mfma16(pa1, bv1, acc[dt]);
        }
        __builtin_amdgcn_s_setprio(0);
    }

    // l total for q = w*16+fr (sum over fq lanes), redistribute to D-layout rows
    float l = lsum;
    l += __shfl_xor(l, 16);
    l += __shfl_xor(l, 32);
    float rlo = 1.0f / l;
    float rl[4];
#pragma unroll
    for (int r = 0; r < 4; ++r)
        rl[r] = __shfl(rlo, fq * 4 + r);

#pragma unroll
    for (int dt = 0; dt < 4; ++dt)
#pragma unroll
        for (int r = 0; r < 4; ++r) {
            int ig = q0 + w * 16 + fq * 4 + r;
            att[((size_t)(b * 1024 + ig) * 12 + h) * 64 + dt * 16 + fr] =
                (u16)cvtpk_bf16(acc[dt][r] * rl[r], 0.f);
        }
}

extern "C" void kernel_launch(void* const* d_in, const int* in_sizes, int n_in,
                              void* d_out, int out_size, void* d_ws, size_t ws_size,
                              hipStream_t stream) {
    const float* x      = (const float*)d_in[0];  // [16,1024,768]
    const float* w_qkv  = (const float*)d_in[1];  // [2304,768]
    const float* b_qkv  = (const float*)d_in[2];  // [2304]
    const float* w_proj = (const float*)d_in[3];  // [768,768]
    const float* b_proj = (const float*)d_in[4];  // [768]
    float* out = (float*)d_out;                   // [16,1024,768]

    char* ws = (char*)d_ws;
    u16* Xb     = (u16*)ws;
    u16* Wqkvb  = (u16*)(ws + 25165824);
    u16* Wprojb = (u16*)(ws + 28704768);
    u16* QKVb   = (u16*)(ws + 29884416);
    u16* Attb   = Xb;  // reuse (Xb consumed before attn writes)

    cvt_all<<<2048, 256, 0, stream>>>(x, w_qkv, w_proj, Xb, Wqkvb, Wprojb);

    gemm_nt<0><<<128 * 18, 512, 0, stream>>>(Xb, Wqkvb, b_qkv, QKVb, nullptr, 18);
    attn_alibi<<<1536, 512, 0, stream>>>(QKVb, Attb);
    gemm_nt<1><<<128 * 6, 512, 0, stream>>>(Attb, Wprojb, b_proj, nullptr, out, 6);
}